// Round 1
// baseline (927.279 us; speedup 1.0000x reference)
//
#include <hip/hip_runtime.h>
#include <hip/hip_bf16.h>
#include <math.h>

#define H_N 16
#define DH 64
#define LSEQ 1024
#define BATCH 2
#define NSLOT 2048
#define DMODEL 1024

// out[C x R] = in[R x C]^T
__global__ __launch_bounds__(256) void k_transpose(const float* __restrict__ in,
                                                   float* __restrict__ out,
                                                   int R, int C) {
    __shared__ float t[32][33];
    int bc = blockIdx.x * 32, br = blockIdx.y * 32;
    int lx = threadIdx.x & 31, ly = threadIdx.x >> 5;  // ly 0..7
#pragma unroll
    for (int i = 0; i < 32; i += 8)
        t[ly + i][lx] = in[(size_t)(br + ly + i) * C + bc + lx];
    __syncthreads();
#pragma unroll
    for (int i = 0; i < 32; i += 8)
        out[(size_t)(bc + ly + i) * R + br + lx] = t[lx][ly + i];
}

// freqs[s][j] = sum_t topo[s][t] * Wfreq[j][t]; cos/sin tables
__global__ __launch_bounds__(256) void k_freq(const float* __restrict__ topo,
                                              const float* __restrict__ Wfreq,
                                              float* __restrict__ cosb,
                                              float* __restrict__ sinb) {
    int s = blockIdx.x * 8 + (threadIdx.x >> 5);
    int j = threadIdx.x & 31;
    float f = 0.f;
#pragma unroll
    for (int t = 0; t < 8; ++t) f += topo[s * 8 + t] * Wfreq[j * 8 + t];
    cosb[s * 32 + j] = cosf(f);
    sinb[s * 32 + j] = sinf(f);
}

// GEMM1: qkv[s][c] = sum_k x[s][k] * Wqkv[c][k]  (WT = Wqkv^T, K-major)
// + RoPE on q,k parts + scatter to (H, slot, Dh) layout.
__global__ __launch_bounds__(256) void k_qkv_rope(
    const float* __restrict__ A, const float* __restrict__ WT,
    const float* __restrict__ cosb, const float* __restrict__ sinb,
    float* __restrict__ Qb, float* __restrict__ Kb, float* __restrict__ Vb) {
    __shared__ float xs[16][256];
    const int tid = threadIdx.x;
    const int c = blockIdx.x * 256 + tid;
    const int s0 = blockIdx.y * 16;
    float acc[16];
#pragma unroll
    for (int r = 0; r < 16; ++r) acc[r] = 0.f;

    for (int k0 = 0; k0 < DMODEL; k0 += 256) {
        __syncthreads();
#pragma unroll
        for (int i = 0; i < 16; ++i)
            xs[i][tid] = A[(size_t)(s0 + i) * DMODEL + k0 + tid];
        __syncthreads();
#pragma unroll 4
        for (int kk4 = 0; kk4 < 64; ++kk4) {
            const float* wp = WT + (size_t)(k0 + kk4 * 4) * 3072 + c;
            float w0 = wp[0];
            float w1 = wp[3072];
            float w2 = wp[2 * 3072];
            float w3 = wp[3 * 3072];
#pragma unroll
            for (int r = 0; r < 16; ++r) {
                float4 x4 = *reinterpret_cast<const float4*>(&xs[r][kk4 * 4]);
                acc[r] = fmaf(x4.w, w3, fmaf(x4.z, w2, fmaf(x4.y, w1, fmaf(x4.x, w0, acc[r]))));
            }
        }
    }

    const int part = c >> 10;        // 0=q 1=k 2=v
    const int h = (c >> 6) & 15;
    const int d = c & 63;
    float* dst = (part == 0) ? Qb : (part == 1) ? Kb : Vb;
#pragma unroll
    for (int r = 0; r < 16; ++r) {
        int s = s0 + r;
        float v = acc[r];
        float partner = __shfl_xor(v, 1);  // other element of the RoPE pair
        float outv;
        if (part < 2) {
            int j = d >> 1;
            float cs = cosb[s * 32 + j], sn = sinb[s * 32 + j];
            // even lane: y1 = x1*cos - x2*sin ; odd lane: y2 = x1*sin + x2*cos
            outv = (d & 1) ? fmaf(v, cs, partner * sn) : fmaf(v, cs, -partner * sn);
        } else {
            outv = v;
        }
        dst[((size_t)h * NSLOT + s) * DH + d] = outv;
    }
}

// Causal attention, one wave per (b, h, query row). Online softmax.
__global__ __launch_bounds__(64) void k_attn(const float* __restrict__ Qb,
                                             const float* __restrict__ Kb,
                                             const float* __restrict__ Vb,
                                             float* __restrict__ AO) {
    const int i = blockIdx.x;   // query position in batch
    const int h = blockIdx.y;
    const int b = blockIdx.z;
    const int lane = threadIdx.x;
    const int s = b * LSEQ + i;

    __shared__ float qs[64];
    __shared__ float ps[64];
    __shared__ float ks[64][65];  // +1 pad: 2-way bank aliasing only (free)

    const float* Kh = Kb + (size_t)h * NSLOT * DH;
    const float* Vh = Vb + (size_t)h * NSLOT * DH;

    qs[lane] = Qb[((size_t)h * NSLOT + s) * DH + lane];
    float m = -INFINITY, l = 0.f, acc = 0.f;
    const int nchunk = (i + 64) / 64;  // ceil((i+1)/64)
    __syncthreads();

    for (int ch = 0; ch < nchunk; ++ch) {
        int sp0 = ch * 64;
        // stage K rows (coalesced: lane = d)
        for (int r = 0; r < 64; ++r)
            ks[r][lane] = Kh[((size_t)(b * LSEQ + sp0 + r)) * DH + lane];
        __syncthreads();

        // phase 1: lane = slot
        float sc = 0.f;
#pragma unroll 16
        for (int d = 0; d < 64; ++d) sc = fmaf(qs[d], ks[lane][d], sc);
        sc *= 0.125f;  // 1/sqrt(64)
        if (sp0 + lane > i) sc = -INFINITY;

        float mx = sc;
#pragma unroll
        for (int off = 32; off > 0; off >>= 1) mx = fmaxf(mx, __shfl_xor(mx, off));
        float newm = fmaxf(m, mx);
        float p = __expf(sc - newm);      // exp(-inf) = 0 handles mask
        float corr = __expf(m - newm);    // first chunk: exp(-inf)=0
        float sum = p;
#pragma unroll
        for (int off = 32; off > 0; off >>= 1) sum += __shfl_xor(sum, off);
        l = l * corr + sum;
        m = newm;
        ps[lane] = p;
        __syncthreads();

        // phase 2: lane = d, V reads coalesced
        float a = 0.f;
#pragma unroll 16
        for (int j2 = 0; j2 < 64; ++j2)
            a = fmaf(ps[j2], Vh[((size_t)(b * LSEQ + sp0 + j2)) * DH + lane], a);
        acc = acc * corr + a;
        __syncthreads();
    }

    AO[(size_t)s * DMODEL + h * DH + lane] = acc / l;
}

// C[s][c] = sum_k A[s][k] * W[c][k]  via WT (K-major). Generic N,K.
__global__ __launch_bounds__(256) void k_gemm_tn(const float* __restrict__ A,
                                                 const float* __restrict__ WT,
                                                 float* __restrict__ C,
                                                 int N, int K) {
    __shared__ float xs[16][256];
    const int tid = threadIdx.x;
    const int c = blockIdx.x * 256 + tid;
    const int s0 = blockIdx.y * 16;
    float acc[16];
#pragma unroll
    for (int r = 0; r < 16; ++r) acc[r] = 0.f;

    for (int k0 = 0; k0 < K; k0 += 256) {
        __syncthreads();
#pragma unroll
        for (int i = 0; i < 16; ++i)
            xs[i][tid] = A[(size_t)(s0 + i) * K + k0 + tid];
        __syncthreads();
#pragma unroll 4
        for (int kk4 = 0; kk4 < 64; ++kk4) {
            const float* wp = WT + (size_t)(k0 + kk4 * 4) * N + c;
            float w0 = wp[0];
            float w1 = wp[N];
            float w2 = wp[2 * N];
            float w3 = wp[3 * N];
#pragma unroll
            for (int r = 0; r < 16; ++r) {
                float4 x4 = *reinterpret_cast<const float4*>(&xs[r][kk4 * 4]);
                acc[r] = fmaf(x4.w, w3, fmaf(x4.z, w2, fmaf(x4.y, w1, fmaf(x4.x, w0, acc[r]))));
            }
        }
    }
#pragma unroll
    for (int r = 0; r < 16; ++r)
        C[(size_t)(s0 + r) * N + c] = acc[r];
}

extern "C" void kernel_launch(void* const* d_in, const int* in_sizes, int n_in,
                              void* d_out, int out_size, void* d_ws, size_t ws_size,
                              hipStream_t stream) {
    const float* x     = (const float*)d_in[0];  // (B, L, D)
    const float* topo  = (const float*)d_in[1];  // (B, L, 8)
    const float* Wqkv  = (const float*)d_in[4];  // (3D, D)
    const float* Wproj = (const float*)d_in[5];  // (D, D)
    const float* Wfreq = (const float*)d_in[6];  // (32, 8)
    float* out = (float*)d_out;                  // (B, L, D) fp32

    float* w = (float*)d_ws;
    float* WTqkv  = w;                  // 1024*3072 = 3,145,728
    float* WTproj = w + 3145728;        // 1024*1024 = 1,048,576
    float* cosb   = w + 4194304;        // 65,536
    float* sinb   = w + 4259840;        // 65,536
    float* Qb     = w + 4325376;        // 16*2048*64 = 2,097,152
    float* Kb     = w + 6422528;
    float* Vb     = w + 8519680;        // ends at 10,616,832 floats (~42.5 MB)
    float* AO     = w;                  // alias WTqkv (dead after GEMM1)

    hipLaunchKernelGGL(k_transpose, dim3(1024 / 32, 3072 / 32), dim3(256), 0, stream,
                       Wqkv, WTqkv, 3072, 1024);
    hipLaunchKernelGGL(k_transpose, dim3(1024 / 32, 1024 / 32), dim3(256), 0, stream,
                       Wproj, WTproj, 1024, 1024);
    hipLaunchKernelGGL(k_freq, dim3(NSLOT / 8), dim3(256), 0, stream,
                       topo, Wfreq, cosb, sinb);
    hipLaunchKernelGGL(k_qkv_rope, dim3(3072 / 256, NSLOT / 16), dim3(256), 0, stream,
                       x, WTqkv, cosb, sinb, Qb, Kb, Vb);
    hipLaunchKernelGGL(k_attn, dim3(LSEQ, H_N, BATCH), dim3(64), 0, stream,
                       Qb, Kb, Vb, AO);
    hipLaunchKernelGGL(k_gemm_tn, dim3(DMODEL / 256, NSLOT / 16), dim3(256), 0, stream,
                       AO, WTproj, out, DMODEL, DMODEL);
}